// Round 6
// baseline (132.380 us; speedup 1.0000x reference)
//
#include <hip/hip_runtime.h>

// ---------------- problem constants ----------------
#define T_LEN   1048576
#define NPAD    1049600            // T_LEN + 2*512
#define NFRAMES 2049
#define BATCH   8
#define NJ      (BATCH * NFRAMES)  // 16392 total frames
#define NSEG    2050               // seg rows per batch
#define SMAX    (BATCH * NSEG - 1) // 16399
#define CUT     513
#define MS_ROWS 514                // basis rows kept: f=0..256 interleaved (re,im)
#define MS_PAD  640                // 5 tiles of 128
#define OUT_BF  (CUT * NFRAMES)
#define NJT     129                // j-tiles of 128
#define PAD_BLOCKS (BATCH * (NPAD / 8) / 256)   // 4100

typedef __attribute__((ext_vector_type(8))) short bf16x8_t;
typedef __attribute__((ext_vector_type(4))) float f32x4_t;
typedef __attribute__((ext_vector_type(4))) int   i32x4_t;

static __device__ __forceinline__ ushort f2bf(float f) {
    union { float f; unsigned u; } a;
    a.f = f;
    unsigned r = a.u + 0x7fffu + ((a.u >> 16) & 1u);
    return (ushort)(r >> 16);
}

static __device__ __forceinline__ void gl_lds16(const ushort* g, ushort* s) {
    __builtin_amdgcn_global_load_lds(
        (__attribute__((address_space(1))) void*)g,
        (__attribute__((address_space(3))) void*)s,
        16, 0, 0);
}

// flip sign of odd-k elements of a bf16x8 fragment (high bf16 of each dword)
static __device__ __forceinline__ bf16x8_t oddflip(bf16x8_t v) {
    i32x4_t w;
    __builtin_memcpy(&w, &v, 16);
    w.x ^= 0x80000000; w.y ^= 0x80000000; w.z ^= 0x80000000; w.w ^= 0x80000000;
    bf16x8_t r;
    __builtin_memcpy(&r, &w, 16);
    return r;
}

// ---------------- merged prep: reflect-pad + basis rearrange ----------------
__global__ void prep_kernel(const float* __restrict__ in, const float* __restrict__ fb,
                            ushort* __restrict__ xpad, ushort* __restrict__ A2) {
    const int tid = threadIdx.x;
    if (blockIdx.x < PAD_BLOCKS) {
        int g  = blockIdx.x * 256 + tid;
        int b  = g / (NPAD / 8);
        int c  = g - b * (NPAD / 8);
        int i0 = c * 8;
        const float* inb = in + (size_t)b * T_LEN;
        ushort o[8];
        if (i0 >= 512 && i0 + 7 < 512 + T_LEN) {
            const float4 v0 = *(const float4*)(inb + (i0 - 512));
            const float4 v1 = *(const float4*)(inb + (i0 - 512) + 4);
            o[0]=f2bf(v0.x); o[1]=f2bf(v0.y); o[2]=f2bf(v0.z); o[3]=f2bf(v0.w);
            o[4]=f2bf(v1.x); o[5]=f2bf(v1.y); o[6]=f2bf(v1.z); o[7]=f2bf(v1.w);
        } else {
            for (int t = 0; t < 8; ++t) {
                int i = i0 + t;
                int src = (i < 512) ? (512 - i)
                        : (i < 512 + T_LEN) ? (i - 512)
                        : (2 * T_LEN + 510 - i);
                o[t] = f2bf(inb[src]);
            }
        }
        *(ulonglong2*)(xpad + (size_t)b * NPAD + i0) = *(ulonglong2*)o;
    } else {
        int g  = (blockIdx.x - PAD_BLOCKS) * 256 + tid;
        int r  = g >> 8;
        int cq = (g & 255) * 4;
        ushort4 o;
        if (r < MS_ROWS) {
            int f = r >> 1, h = r & 1;     // f <= 256
            const float4 v = *(const float4*)(fb + (size_t)(f + h * CUT) * 1024 + cq);
            o = make_ushort4(f2bf(v.x), f2bf(v.y), f2bf(v.z), f2bf(v.w));
        } else {
            o = make_ushort4(0, 0, 0, 0);
        }
        *(ushort4*)(A2 + (size_t)r * 1024 + cq) = o;
    }
}

// ------- GEMM (hop-split, BK=64, XOR-swizzled LDS, XCD grid, DFT symmetry) -------
// acc1[m][j] = A2[m] . frame_j ;  acc2[m][j] = A2[m] . ((-1)^k frame_j)
// out[f]      from acc1 (f = M>>1 <= 256)
// out[512-f]  from acc2 (sign of imag irrelevant under magnitude)
__global__ __launch_bounds__(256, 2) void gemm_kernel(
        const ushort* __restrict__ A2, const ushort* __restrict__ xpad,
        float* __restrict__ out, const float* __restrict__ epsp) {
    __shared__ __align__(16) ushort ldsA0[128 * 64];
    __shared__ __align__(16) ushort ldsA1[128 * 64];
    __shared__ __align__(16) ushort ldsB [136 * 64];

    // XCD swizzle: the 5 m-blocks of one j-tile share bid%8 -> same XCD L2
    const int bid = blockIdx.x;
    const int jt  = (bid / 40) * 8 + (bid & 7);
    const int mt  = (bid >> 3) % 5;
    if (jt >= NJT) return;                 // uniform early-exit (before any barrier)

    const int tid  = threadIdx.x;
    const int wave = tid >> 6, lane = tid & 63;
    const int quad = lane >> 4, l15 = lane & 15;
    const int m0 = mt * 128;
    const int j0 = jt * 128;
    const int wm = (wave >> 1) * 64;
    const int wj = (wave & 1) * 64;

    const int b0 = j0 / NFRAMES;
    const int S0 = j0 + b0;                // global seg index of LDS B row 0

    const int sr  = lane >> 3;             // staged row within 8-row group
    const int sc8 = ((lane & 7) ^ sr) * 8; // XOR-swizzled source chunk (elems)

    int aoff[4], boff[4], boffx = 0;
    for (int t = 0; t < 4; ++t) {
        const int r = (wave * 4 + t) * 8 + sr;
        aoff[t] = (m0 + r) * 1024 + sc8;
        int S = S0 + r; if (S > SMAX) S = SMAX;
        int bb = S / NSEG, ss = S - bb * NSEG;
        boff[t] = bb * NPAD + ss * 512 + sc8;
    }
    {
        int S = S0 + 128 + sr; if (S > SMAX) S = SMAX;
        int bb = S / NSEG, ss = S - bb * NSEG;
        boffx = bb * NPAD + ss * 512 + sc8;
    }

    // per-lane B fragment base rows (handles batch-boundary shift)
    int rowb[4];
    for (int jx = 0; jx < 4; ++jx) {
        const int j = j0 + wj + jx * 16 + l15;
        rowb[jx] = wj + jx * 16 + l15 + (j / NFRAMES - b0);
    }

    f32x4_t acc1[4][4] = {};
    f32x4_t acc2[4][4] = {};

    for (int kt = 0; kt < 8; ++kt) {
        const int k0 = kt * 64;
        __syncthreads();
        for (int t = 0; t < 4; ++t) {
            gl_lds16(A2 + aoff[t] + k0,        &ldsA0[(wave * 4 + t) * 512]);
            gl_lds16(A2 + aoff[t] + 512 + k0,  &ldsA1[(wave * 4 + t) * 512]);
            gl_lds16(xpad + boff[t] + k0,      &ldsB [(wave * 4 + t) * 512]);
        }
        if (wave == 0) gl_lds16(xpad + boffx + k0, &ldsB[16 * 512]);
        __syncthreads();
        for (int kk = 0; kk < 2; ++kk) {
            const int cb = kk * 4 + quad;      // within-window chunk 0..7
            bf16x8_t a0[4], a1[4], bf0[4], bf1[4];
            const int asw = (cb ^ (l15 & 7)) * 8;
            for (int i = 0; i < 4; ++i) {
                const int ro = (wm + i * 16 + l15) * 64;
                a0[i] = *(const bf16x8_t*)&ldsA0[ro + asw];
                a1[i] = *(const bf16x8_t*)&ldsA1[ro + asw];
            }
            for (int jx = 0; jx < 4; ++jx) {
                const int r0 = rowb[jx];
                const int r1 = r0 + 1;
                bf0[jx] = *(const bf16x8_t*)&ldsB[r0 * 64 + ((cb ^ (r0 & 7)) * 8)];
                bf1[jx] = *(const bf16x8_t*)&ldsB[r1 * 64 + ((cb ^ (r1 & 7)) * 8)];
            }
            // direct variant
            for (int i = 0; i < 4; ++i)
                for (int jx = 0; jx < 4; ++jx) {
                    acc1[i][jx] = __builtin_amdgcn_mfma_f32_16x16x32_bf16(
                        a0[i], bf0[jx], acc1[i][jx], 0, 0, 0);
                    acc1[i][jx] = __builtin_amdgcn_mfma_f32_16x16x32_bf16(
                        a1[i], bf1[jx], acc1[i][jx], 0, 0, 0);
                }
            // mirrored variant: (-1)^k modulated B (k=512+k' has same parity as k')
            for (int jx = 0; jx < 4; ++jx) {
                bf0[jx] = oddflip(bf0[jx]);
                bf1[jx] = oddflip(bf1[jx]);
            }
            for (int i = 0; i < 4; ++i)
                for (int jx = 0; jx < 4; ++jx) {
                    acc2[i][jx] = __builtin_amdgcn_mfma_f32_16x16x32_bf16(
                        a0[i], bf0[jx], acc2[i][jx], 0, 0, 0);
                    acc2[i][jx] = __builtin_amdgcn_mfma_f32_16x16x32_bf16(
                        a1[i], bf1[jx], acc2[i][jx], 0, 0, 0);
                }
        }
    }

    // epilogue: C/D layout col=lane&15 (-> j), row=quad*4+reg (-> M); M%4==0
    const float eps = *epsp;
    for (int tj = 0; tj < 4; ++tj) {
        const int j = j0 + wj + tj * 16 + l15;
        if (j >= NJ) continue;
        const int b = j / NFRAMES;
        const int n = j - b * NFRAMES;
        float* ob = out + (size_t)b * OUT_BF + n;
        for (int ti = 0; ti < 4; ++ti) {
            const int M  = m0 + wm + ti * 16 + quad * 4;
            const int f0 = M >> 1;             // even, pairs (f0, f0+1)
            f32x4_t c1 = acc1[ti][tj];
            f32x4_t c2 = acc2[ti][tj];
            if (f0 <= 256) {
                ob[(size_t)f0 * NFRAMES] =
                    sqrtf(c1.x * c1.x + c1.y * c1.y + eps);
                ob[(size_t)(512 - f0) * NFRAMES] =
                    sqrtf(c2.x * c2.x + c2.y * c2.y + eps);
            }
            if (f0 + 1 <= 256) {
                ob[(size_t)(f0 + 1) * NFRAMES] =
                    sqrtf(c1.z * c1.z + c1.w * c1.w + eps);
                ob[(size_t)(511 - f0) * NFRAMES] =
                    sqrtf(c2.z * c2.z + c2.w * c2.w + eps);
            }
        }
    }
}

extern "C" void kernel_launch(void* const* d_in, const int* in_sizes, int n_in,
                              void* d_out, int out_size, void* d_ws, size_t ws_size,
                              hipStream_t stream) {
    const float* in   = (const float*)d_in[0];
    const float* fb   = (const float*)d_in[1];
    const float* epsp = (const float*)d_in[2];
    float* out = (float*)d_out;

    ushort* A2   = (ushort*)d_ws;                                      // 640*1024*2B
    ushort* xpad = (ushort*)((char*)d_ws + (size_t)MS_PAD * 1024 * 2); // 8*NPAD*2B

    prep_kernel<<<dim3(PAD_BLOCKS + MS_PAD), dim3(256), 0, stream>>>(in, fb, xpad, A2);
    // grid: 17 groups x (8 j-tiles x 5 m-tiles); blocks with jt>=129 early-exit
    gemm_kernel<<<dim3(17 * 40), dim3(256), 0, stream>>>(A2, xpad, out, epsp);
}